// Round 1
// baseline (278.878 us; speedup 1.0000x reference)
//
#include <hip/hip_runtime.h>

#define N_BR   4
#define BATCH  8192
#define DIM    4096
#define NCLS   1024
#define MARGIN 0.3f
#define EPS_P  1e-8f

typedef __attribute__((ext_vector_type(4))) float f32x4;
typedef __attribute__((ext_vector_type(8))) short short8;
typedef unsigned short u16;

struct alignas(8) U16x4 { u16 x, y, z, w; };

__device__ __forceinline__ u16 f2bf(float x) {
  unsigned u = __float_as_uint(x);
  u += 0x7FFFu + ((u >> 16) & 1u);   // round-to-nearest-even
  return (u16)(u >> 16);
}

// ---------------- init: zero counts, hardneg = +inf ----------------
__global__ void initk(int* counts, unsigned int* hn) {
  int i = blockIdx.x * blockDim.x + threadIdx.x;
  if (i < NCLS) counts[i] = 0;
  if (i < N_BR * NCLS) hn[i] = 0x7F800000u;  // +inf bits
}

// ---------------- count targets (int atomics: deterministic) ----------------
__global__ void countk(const int* __restrict__ targets, int* __restrict__ counts) {
  int b = blockIdx.x * blockDim.x + threadIdx.x;
  if (b < BATCH) atomicAdd(&counts[targets[b]], 1);
}

// ---------------- exclusive scan over 1024 counts ----------------
__global__ void scank(const int* __restrict__ counts, int* __restrict__ offs) {
  __shared__ int tmp[NCLS];
  int tid = threadIdx.x;
  int v = counts[tid];
  tmp[tid] = v;
  __syncthreads();
  for (int off = 1; off < NCLS; off <<= 1) {
    int t = (tid >= off) ? tmp[tid - off] : 0;
    __syncthreads();
    tmp[tid] += t;
    __syncthreads();
  }
  offs[tid] = tmp[tid] - v;                 // exclusive prefix
  if (tid == NCLS - 1) offs[NCLS] = tmp[tid];
}

// ---------------- deterministic CSR scatter (ballot-prefix, b-ordered) ------
__global__ void scatterk(const int* __restrict__ targets,
                         const int* __restrict__ offs,
                         int* __restrict__ members) {
  int c = blockIdx.x;
  int lane = threadIdx.x;                   // 64 threads = 1 wave
  int base = offs[c];
  int pos = 0;
  for (int b0 = 0; b0 < BATCH; b0 += 64) {
    int b = b0 + lane;
    bool m = (targets[b] == c);
    unsigned long long mask = __ballot(m);
    if (m) {
      int p = pos + __popcll(mask & ((1ULL << lane) - 1ULL));
      members[base + p] = b;
    }
    pos += __popcll(mask);
  }
}

// ---------------- centers (fp32 + bf16 copy) and sq = ||c||^2 ----------------
__global__ __launch_bounds__(256) void centersk(
    const float* __restrict__ feats, const int* __restrict__ members,
    const int* __restrict__ offs, float* __restrict__ centers,
    u16* __restrict__ cbf, float* __restrict__ sq) {
  int c = blockIdx.x, n = blockIdx.y, tid = threadIdx.x;
  int beg = offs[c], end = offs[c + 1];
  float inv = 1.0f / (float)(end - beg);
  const float* fb = feats + (size_t)n * BATCH * DIM;
  size_t cbase = ((size_t)n * NCLS + c) * DIM;
  float ssq = 0.f;
#pragma unroll
  for (int it = 0; it < DIM / 1024; ++it) {     // 4 iterations of float4
    int d = (it * 256 + tid) * 4;
    f32x4 acc = {0.f, 0.f, 0.f, 0.f};
    for (int m = beg; m < end; ++m) {
      int b = members[m];
      f32x4 v = *(const f32x4*)(fb + (size_t)b * DIM + d);
      acc += v;
    }
    f32x4 ctr = acc * inv;
    *(f32x4*)(centers + cbase + d) = ctr;
    U16x4 h;
    h.x = f2bf(ctr.x); h.y = f2bf(ctr.y); h.z = f2bf(ctr.z); h.w = f2bf(ctr.w);
    *(U16x4*)(cbf + cbase + d) = h;
    ssq += ctr.x * ctr.x + ctr.y * ctr.y + ctr.z * ctr.z + ctr.w * ctr.w;
  }
  for (int off = 1; off < 64; off <<= 1) ssq += __shfl_xor(ssq, off, 64);
  __shared__ float rs[4];
  if ((tid & 63) == 0) rs[tid >> 6] = ssq;
  __syncthreads();
  if (tid == 0) sq[n * NCLS + c] = rs[0] + rs[1] + rs[2] + rs[3];
}

// ---------------- gram via bf16 MFMA + fused hard-neg min ----------------
// 128x128 tile, BK=64, 4 waves (2x2), each wave 64x64 (4x4 frags of 16x16).
// LDS XOR-swizzle via pre-swizzled global source (G4/T2, rule 21).
__global__ __launch_bounds__(256) void gramk(
    const u16* __restrict__ cbf, const float* __restrict__ sq,
    unsigned int* __restrict__ hn) {
  __shared__ u16 As[128 * 64];
  __shared__ u16 Bs[128 * 64];
  int bi = blockIdx.x, bj = blockIdx.y, n = blockIdx.z;
  int tid = threadIdx.x;
  int wid = tid >> 6, lane = tid & 63;
  int wr = wid >> 1, wc = wid & 1;
  int r0 = bi * 128, c0 = bj * 128;
  const u16* base = cbf + (size_t)n * NCLS * DIM;

  f32x4 acc[4][4] = {};

  for (int kb = 0; kb < DIM; kb += 64) {
#pragma unroll
    for (int it = 0; it < 4; ++it) {
      int g = it * 256 + tid;              // 16B chunk id, wave-contiguous
      int row = g >> 3, cir = g & 7;
      int scir = cir ^ (row & 7);          // inverse-swizzled SOURCE chunk
      const u16* gA = base + (size_t)(r0 + row) * DIM + kb + scir * 8;
      const u16* gB = base + (size_t)(c0 + row) * DIM + kb + scir * 8;
      __builtin_amdgcn_global_load_lds(
          (const __attribute__((address_space(1))) void*)gA,
          (__attribute__((address_space(3))) void*)(As + g * 8), 16, 0, 0);
      __builtin_amdgcn_global_load_lds(
          (const __attribute__((address_space(1))) void*)gB,
          (__attribute__((address_space(3))) void*)(Bs + g * 8), 16, 0, 0);
    }
    __syncthreads();
#pragma unroll
    for (int ks = 0; ks < 2; ++ks) {
      short8 a[4], b[4];
      int co = ks * 4 + (lane >> 4);       // k-chunk this lane reads
#pragma unroll
      for (int mi = 0; mi < 4; ++mi) {
        int r = wr * 64 + mi * 16 + (lane & 15);
        a[mi] = *(const short8*)(As + r * 64 + (co ^ (r & 7)) * 8);
      }
#pragma unroll
      for (int nj = 0; nj < 4; ++nj) {
        int r = wc * 64 + nj * 16 + (lane & 15);
        b[nj] = *(const short8*)(Bs + r * 64 + (co ^ (r & 7)) * 8);
      }
#pragma unroll
      for (int mi = 0; mi < 4; ++mi)
#pragma unroll
        for (int nj = 0; nj < 4; ++nj)
          acc[mi][nj] = __builtin_amdgcn_mfma_f32_16x16x32_bf16(
              a[mi], b[nj], acc[mi][nj], 0, 0, 0);
    }
    __syncthreads();
  }

  // epilogue: dist = sqrt(max(sq[r]+sq[c]-2g,0)); min over cols; atomicMin
  const float* sqn = sq + n * NCLS;
  int grp = lane >> 4, lid = lane & 15;
#pragma unroll
  for (int mi = 0; mi < 4; ++mi) {
#pragma unroll
    for (int j = 0; j < 4; ++j) {
      int rr = r0 + wr * 64 + mi * 16 + grp * 4 + j;
      float sqr = sqn[rr];
      float dmin = __builtin_inff();
#pragma unroll
      for (int nj = 0; nj < 4; ++nj) {
        int cc = c0 + wc * 64 + nj * 16 + lid;
        float g = acc[mi][nj][j];
        float d2 = sqr + sqn[cc] - 2.0f * g;
        float dist = (rr == cc) ? __builtin_inff() : sqrtf(fmaxf(d2, 0.f));
        dmin = fminf(dmin, dist);
      }
#pragma unroll
      for (int off = 1; off < 16; off <<= 1)
        dmin = fminf(dmin, __shfl_xor(dmin, off, 64));
      if (lid == 0)
        atomicMin(&hn[n * NCLS + rr], __float_as_uint(dmin));
    }
  }
}

// ---------------- pos distances + per-class partial loss ----------------
__global__ __launch_bounds__(256) void posk(
    const float* __restrict__ centers, const unsigned int* __restrict__ hn,
    float* __restrict__ partial) {
  int c = blockIdx.x, tid = threadIdx.x;
  const int ii[6] = {0, 0, 0, 1, 1, 2};
  const int jj[6] = {1, 2, 3, 2, 3, 3};
  float s[6] = {0.f, 0.f, 0.f, 0.f, 0.f, 0.f};
#pragma unroll
  for (int it = 0; it < DIM / 1024; ++it) {
    int d = (it * 256 + tid) * 4;
    f32x4 v[N_BR];
#pragma unroll
    for (int nb = 0; nb < N_BR; ++nb)
      v[nb] = *(const f32x4*)(centers + ((size_t)nb * NCLS + c) * DIM + d);
#pragma unroll
    for (int p = 0; p < 6; ++p) {
#pragma unroll
      for (int e = 0; e < 4; ++e) {
        float df = v[ii[p]][e] - v[jj[p]][e] + EPS_P;
        s[p] += df * df;
      }
    }
  }
  __shared__ float red[4][6];
#pragma unroll
  for (int p = 0; p < 6; ++p) {
    float x = s[p];
    for (int off = 1; off < 64; off <<= 1) x += __shfl_xor(x, off, 64);
    if ((tid & 63) == 0) red[tid >> 6][p] = x;
  }
  __syncthreads();
  if (tid == 0) {
    float total = 0.f;
#pragma unroll
    for (int p = 0; p < 6; ++p) {
      float sum = red[0][p] + red[1][p] + red[2][p] + red[3][p];
      float pos = sqrtf(sum);
      float hneg = __uint_as_float(hn[ii[p] * NCLS + c]);
      float t = MARGIN + pos - hneg;
      total += fmaxf(t, 0.f);
    }
    partial[c] = total;
  }
}

// ---------------- deterministic final reduction ----------------
__global__ void finalk(const float* __restrict__ partial, float* __restrict__ out) {
  int tid = threadIdx.x;  // 256
  float s = 0.f;
  for (int c = tid; c < NCLS; c += 256) s += partial[c];
  for (int off = 1; off < 64; off <<= 1) s += __shfl_xor(s, off, 64);
  __shared__ float rs[4];
  if ((tid & 63) == 0) rs[tid >> 6] = s;
  __syncthreads();
  if (tid == 0) out[0] = (rs[0] + rs[1] + rs[2] + rs[3]) * (1.0f / (6.0f * NCLS));
}

extern "C" void kernel_launch(void* const* d_in, const int* in_sizes, int n_in,
                              void* d_out, int out_size, void* d_ws, size_t ws_size,
                              hipStream_t stream) {
  const float* feats = (const float*)d_in[0];
  const int* targets = (const int*)d_in[1];
  float* out = (float*)d_out;
  char* ws = (char*)d_ws;

  // workspace layout (bytes)
  int* counts      = (int*)(ws + 0);                   //  4 KB
  int* offs        = (int*)(ws + 4096);                //  ~4.1 KB
  int* members     = (int*)(ws + 12288);               // 32 KB
  float* sq        = (float*)(ws + 45056);             // 16 KB
  unsigned int* hn = (unsigned int*)(ws + 61440);      // 16 KB
  float* partial   = (float*)(ws + 77824);             //  4 KB
  float* centers   = (float*)(ws + 131072);            // 67,108,864
  u16* cbf         = (u16*)(ws + 131072 + 67108864);   // 33,554,432

  hipLaunchKernelGGL(initk, dim3(16), dim3(256), 0, stream, counts, hn);
  hipLaunchKernelGGL(countk, dim3(BATCH / 256), dim3(256), 0, stream, targets, counts);
  hipLaunchKernelGGL(scank, dim3(1), dim3(NCLS), 0, stream, counts, offs);
  hipLaunchKernelGGL(scatterk, dim3(NCLS), dim3(64), 0, stream, targets, offs, members);
  hipLaunchKernelGGL(centersk, dim3(NCLS, N_BR), dim3(256), 0, stream,
                     feats, members, offs, centers, cbf, sq);
  hipLaunchKernelGGL(gramk, dim3(NCLS / 128, NCLS / 128, N_BR), dim3(256), 0, stream,
                     cbf, sq, hn);
  hipLaunchKernelGGL(posk, dim3(NCLS), dim3(256), 0, stream, centers, hn, partial);
  hipLaunchKernelGGL(finalk, dim3(1), dim3(256), 0, stream, partial, out);
}

// Round 2
// 214.403 us; speedup vs baseline: 1.3007x; 1.3007x over previous
//
#include <hip/hip_runtime.h>

#define N_BR   4
#define BATCH  8192
#define DIM    4096
#define NCLS   1024
#define MARGIN 0.3f
#define EPS_P  1e-8f

typedef __attribute__((ext_vector_type(4))) float f32x4;
typedef __attribute__((ext_vector_type(8))) short short8;
typedef unsigned short u16;

struct alignas(8) U16x4 { u16 x, y, z, w; };

__device__ __forceinline__ u16 f2bf(float x) {
  unsigned u = __float_as_uint(x);
  u += 0x7FFFu + ((u >> 16) & 1u);   // round-to-nearest-even
  return (u16)(u >> 16);
}
__device__ __forceinline__ float bf2f(u16 h) {
  return __uint_as_float(((unsigned)h) << 16);
}

// ---------------- init: zero counts, hardneg = +inf ----------------
__global__ void initk(int* counts, unsigned int* hn) {
  int i = blockIdx.x * blockDim.x + threadIdx.x;
  if (i < NCLS) counts[i] = 0;
  if (i < N_BR * NCLS) hn[i] = 0x7F800000u;  // +inf bits
}

// ---------------- count targets (int atomics: deterministic) ----------------
__global__ void countk(const int* __restrict__ targets, int* __restrict__ counts) {
  int b = blockIdx.x * blockDim.x + threadIdx.x;
  if (b < BATCH) atomicAdd(&counts[targets[b]], 1);
}

// ---------------- exclusive scan over 1024 counts ----------------
__global__ void scank(const int* __restrict__ counts, int* __restrict__ offs) {
  __shared__ int tmp[NCLS];
  int tid = threadIdx.x;
  int v = counts[tid];
  tmp[tid] = v;
  __syncthreads();
  for (int off = 1; off < NCLS; off <<= 1) {
    int t = (tid >= off) ? tmp[tid - off] : 0;
    __syncthreads();
    tmp[tid] += t;
    __syncthreads();
  }
  offs[tid] = tmp[tid] - v;                 // exclusive prefix
  if (tid == NCLS - 1) offs[NCLS] = tmp[tid];
}

// ---------------- deterministic CSR scatter (ballot-prefix, b-ordered) ------
__global__ void scatterk(const int* __restrict__ targets,
                         const int* __restrict__ offs,
                         int* __restrict__ members) {
  int c = blockIdx.x;
  int lane = threadIdx.x;                   // 64 threads = 1 wave
  int base = offs[c];
  int pos = 0;
  for (int b0 = 0; b0 < BATCH; b0 += 64) {
    int b = b0 + lane;
    bool m = (targets[b] == c);
    unsigned long long mask = __ballot(m);
    if (m) {
      int p = pos + __popcll(mask & ((1ULL << lane) - 1ULL));
      members[base + p] = b;
    }
    pos += __popcll(mask);
  }
}

// ---------------- centers (bf16 only) and sq = ||c||^2 (fp32) ----------------
__global__ __launch_bounds__(256) void centersk(
    const float* __restrict__ feats, const int* __restrict__ members,
    const int* __restrict__ offs, u16* __restrict__ cbf,
    float* __restrict__ sq) {
  int c = blockIdx.x, n = blockIdx.y, tid = threadIdx.x;
  int beg = offs[c], end = offs[c + 1];
  float inv = 1.0f / (float)(end - beg);
  const float* fb = feats + (size_t)n * BATCH * DIM;
  size_t cbase = ((size_t)n * NCLS + c) * DIM;
  float ssq = 0.f;
#pragma unroll
  for (int it = 0; it < DIM / 1024; ++it) {     // 4 iterations of float4
    int d = (it * 256 + tid) * 4;
    f32x4 acc = {0.f, 0.f, 0.f, 0.f};
    for (int m = beg; m < end; ++m) {
      int b = members[m];
      f32x4 v = *(const f32x4*)(fb + (size_t)b * DIM + d);
      acc += v;
    }
    f32x4 ctr = acc * inv;
    U16x4 h;
    h.x = f2bf(ctr.x); h.y = f2bf(ctr.y); h.z = f2bf(ctr.z); h.w = f2bf(ctr.w);
    *(U16x4*)(cbf + cbase + d) = h;
    ssq += ctr.x * ctr.x + ctr.y * ctr.y + ctr.z * ctr.z + ctr.w * ctr.w;
  }
  for (int off = 1; off < 64; off <<= 1) ssq += __shfl_xor(ssq, off, 64);
  __shared__ float rs[4];
  if ((tid & 63) == 0) rs[tid >> 6] = ssq;
  __syncthreads();
  if (tid == 0) sq[n * NCLS + c] = rs[0] + rs[1] + rs[2] + rs[3];
}

// ---------------- gram via bf16 MFMA, upper-triangular tiles only ----------
// 64x64 tile, 4 waves (2x2), each wave 32x32 (2x2 frags of 16x16x32).
// Row-min AND col-min both feed hn via atomicMin (symmetry).
__global__ __launch_bounds__(256) void gramk(
    const u16* __restrict__ cbf, const float* __restrict__ sq,
    unsigned int* __restrict__ hn) {
  __shared__ u16 As[64 * 64];
  __shared__ u16 Bs[64 * 64];
  int x = blockIdx.x;                      // 0..135 upper-tile id
  int n = blockIdx.y;
  int ti = 0;
  while (x >= 16 - ti) { x -= 16 - ti; ++ti; }
  int tj = ti + x;                         // ti <= tj
  int tid = threadIdx.x;
  int wid = tid >> 6, lane = tid & 63;
  int wr = wid >> 1, wc = wid & 1;
  int r0 = ti * 64, c0 = tj * 64;
  const u16* base = cbf + (size_t)n * NCLS * DIM;

  f32x4 acc[2][2] = {};

  for (int kb = 0; kb < DIM; kb += 64) {
#pragma unroll
    for (int it = 0; it < 2; ++it) {
      int g = it * 256 + tid;              // 16B chunk id: [row][cir]
      int row = g >> 3, cir = g & 7;
      int scir = cir ^ (row & 7);          // inverse-swizzled SOURCE chunk
      const u16* gA = base + (size_t)(r0 + row) * DIM + kb + scir * 8;
      const u16* gB = base + (size_t)(c0 + row) * DIM + kb + scir * 8;
      __builtin_amdgcn_global_load_lds(
          (const __attribute__((address_space(1))) void*)gA,
          (__attribute__((address_space(3))) void*)(As + g * 8), 16, 0, 0);
      __builtin_amdgcn_global_load_lds(
          (const __attribute__((address_space(1))) void*)gB,
          (__attribute__((address_space(3))) void*)(Bs + g * 8), 16, 0, 0);
    }
    __syncthreads();
#pragma unroll
    for (int ks = 0; ks < 2; ++ks) {
      short8 a[2], b[2];
      int co = ks * 4 + (lane >> 4);       // k-chunk this lane reads
#pragma unroll
      for (int mi = 0; mi < 2; ++mi) {
        int r = wr * 32 + mi * 16 + (lane & 15);
        a[mi] = *(const short8*)(As + r * 64 + (co ^ (r & 7)) * 8);
      }
#pragma unroll
      for (int nj = 0; nj < 2; ++nj) {
        int r = wc * 32 + nj * 16 + (lane & 15);
        b[nj] = *(const short8*)(Bs + r * 64 + (co ^ (r & 7)) * 8);
      }
#pragma unroll
      for (int mi = 0; mi < 2; ++mi)
#pragma unroll
        for (int nj = 0; nj < 2; ++nj)
          acc[mi][nj] = __builtin_amdgcn_mfma_f32_16x16x32_bf16(
              a[mi], b[nj], acc[mi][nj], 0, 0, 0);
    }
    __syncthreads();
  }

  // epilogue: dist = sqrt(max(sq[r]+sq[c]-2g,0)), diag -> inf
  const float* sqn = sq + n * NCLS;
  unsigned int* hb = hn + n * NCLS;
  int grp = lane >> 4, lid = lane & 15;
  float dist[2][2][4];
#pragma unroll
  for (int mi = 0; mi < 2; ++mi)
#pragma unroll
    for (int nj = 0; nj < 2; ++nj)
#pragma unroll
      for (int j = 0; j < 4; ++j) {
        int rr = r0 + wr * 32 + mi * 16 + grp * 4 + j;
        int cc = c0 + wc * 32 + nj * 16 + lid;
        float d2 = sqn[rr] + sqn[cc] - 2.0f * acc[mi][nj][j];
        dist[mi][nj][j] = (rr == cc) ? __builtin_inff()
                                     : sqrtf(fmaxf(d2, 0.f));
      }
  // row-min (min over cols of this tile) -> hn[row]
#pragma unroll
  for (int mi = 0; mi < 2; ++mi)
#pragma unroll
    for (int j = 0; j < 4; ++j) {
      float dmin = fminf(dist[mi][0][j], dist[mi][1][j]);
#pragma unroll
      for (int off = 1; off < 16; off <<= 1)
        dmin = fminf(dmin, __shfl_xor(dmin, off, 64));
      if (lid == 0) {
        int rr = r0 + wr * 32 + mi * 16 + grp * 4 + j;
        atomicMin(&hb[rr], __float_as_uint(dmin));
      }
    }
  // col-min (min over rows of this tile) -> hn[col]  (symmetry)
#pragma unroll
  for (int nj = 0; nj < 2; ++nj) {
    float cmin = __builtin_inff();
#pragma unroll
    for (int mi = 0; mi < 2; ++mi)
#pragma unroll
      for (int j = 0; j < 4; ++j)
        cmin = fminf(cmin, dist[mi][nj][j]);
    cmin = fminf(cmin, __shfl_xor(cmin, 16, 64));
    cmin = fminf(cmin, __shfl_xor(cmin, 32, 64));
    if (grp == 0) {
      int cc = c0 + wc * 32 + nj * 16 + lid;
      atomicMin(&hb[cc], __float_as_uint(cmin));
    }
  }
}

// ---------------- pos distances (bf16 centers) + per-class partial loss -----
__global__ __launch_bounds__(256) void posk(
    const u16* __restrict__ cbf, const unsigned int* __restrict__ hn,
    float* __restrict__ partial) {
  int c = blockIdx.x, tid = threadIdx.x;
  const int ii[6] = {0, 0, 0, 1, 1, 2};
  const int jj[6] = {1, 2, 3, 2, 3, 3};
  float s[6] = {0.f, 0.f, 0.f, 0.f, 0.f, 0.f};
#pragma unroll
  for (int it = 0; it < DIM / 2048; ++it) {   // 2 iterations of 8-wide bf16
    int d = (it * 256 + tid) * 8;
    float v[N_BR][8];
#pragma unroll
    for (int nb = 0; nb < N_BR; ++nb) {
      short8 h = *(const short8*)(cbf + ((size_t)nb * NCLS + c) * DIM + d);
#pragma unroll
      for (int e = 0; e < 8; ++e) v[nb][e] = bf2f((u16)h[e]);
    }
#pragma unroll
    for (int p = 0; p < 6; ++p) {
#pragma unroll
      for (int e = 0; e < 8; ++e) {
        float df = v[ii[p]][e] - v[jj[p]][e] + EPS_P;
        s[p] += df * df;
      }
    }
  }
  __shared__ float red[4][6];
#pragma unroll
  for (int p = 0; p < 6; ++p) {
    float x = s[p];
    for (int off = 1; off < 64; off <<= 1) x += __shfl_xor(x, off, 64);
    if ((tid & 63) == 0) red[tid >> 6][p] = x;
  }
  __syncthreads();
  if (tid == 0) {
    float total = 0.f;
#pragma unroll
    for (int p = 0; p < 6; ++p) {
      float sum = red[0][p] + red[1][p] + red[2][p] + red[3][p];
      float pos = sqrtf(sum);
      float hneg = __uint_as_float(hn[ii[p] * NCLS + c]);
      float t = MARGIN + pos - hneg;
      total += fmaxf(t, 0.f);
    }
    partial[c] = total;
  }
}

// ---------------- deterministic final reduction ----------------
__global__ void finalk(const float* __restrict__ partial, float* __restrict__ out) {
  int tid = threadIdx.x;  // 256
  float s = 0.f;
  for (int c = tid; c < NCLS; c += 256) s += partial[c];
  for (int off = 1; off < 64; off <<= 1) s += __shfl_xor(s, off, 64);
  __shared__ float rs[4];
  if ((tid & 63) == 0) rs[tid >> 6] = s;
  __syncthreads();
  if (tid == 0) out[0] = (rs[0] + rs[1] + rs[2] + rs[3]) * (1.0f / (6.0f * NCLS));
}

extern "C" void kernel_launch(void* const* d_in, const int* in_sizes, int n_in,
                              void* d_out, int out_size, void* d_ws, size_t ws_size,
                              hipStream_t stream) {
  const float* feats = (const float*)d_in[0];
  const int* targets = (const int*)d_in[1];
  float* out = (float*)d_out;
  char* ws = (char*)d_ws;

  // workspace layout (bytes)
  int* counts      = (int*)(ws + 0);                   //  4 KB
  int* offs        = (int*)(ws + 4096);                //  ~4.1 KB
  int* members     = (int*)(ws + 12288);               // 32 KB
  float* sq        = (float*)(ws + 45056);             // 16 KB
  unsigned int* hn = (unsigned int*)(ws + 61440);      // 16 KB
  float* partial   = (float*)(ws + 77824);             //  4 KB
  u16* cbf         = (u16*)(ws + 131072);              // 33,554,432

  hipLaunchKernelGGL(initk, dim3(16), dim3(256), 0, stream, counts, hn);
  hipLaunchKernelGGL(countk, dim3(BATCH / 256), dim3(256), 0, stream, targets, counts);
  hipLaunchKernelGGL(scank, dim3(1), dim3(NCLS), 0, stream, counts, offs);
  hipLaunchKernelGGL(scatterk, dim3(NCLS), dim3(64), 0, stream, targets, offs, members);
  hipLaunchKernelGGL(centersk, dim3(NCLS, N_BR), dim3(256), 0, stream,
                     feats, members, offs, cbf, sq);
  hipLaunchKernelGGL(gramk, dim3(136, N_BR), dim3(256), 0, stream, cbf, sq, hn);
  hipLaunchKernelGGL(posk, dim3(NCLS), dim3(256), 0, stream, cbf, hn, partial);
  hipLaunchKernelGGL(finalk, dim3(1), dim3(256), 0, stream, partial, out);
}